// Round 2
// baseline (745.556 us; speedup 1.0000x reference)
//
#include <hip/hip_runtime.h>
#include <hip/hip_bf16.h>
#include <string.h>

#define B_ 256
#define L_ 512
#define H_ 768
#define K_ 64
#define WT_OFF 33554432   // emit = 131072*64*4 bytes, Wt after it

typedef float  float4v  __attribute__((ext_vector_type(4)));
typedef float  float2v  __attribute__((ext_vector_type(2)));
typedef short  short8v  __attribute__((ext_vector_type(8)));

union BFragU { uint4 u4; short8v s8; };

__device__ inline unsigned short f2bf_bits(float f) {
    union { float f; unsigned int u; } c; c.f = f;
    unsigned int u = c.u;
    u += 0x7fffu + ((u >> 16) & 1u);   // round-to-nearest-even
    return (unsigned short)(u >> 16);
}

__device__ inline float2v mk2(float x, float y) { float2v v; v.x = x; v.y = y; return v; }

// ---------------------------------------------------------------------------
// Kernel 0: Wt[k][h] = bf16(W[h][k])  (64 x 768 bf16 = 96 KB in d_ws)
// ---------------------------------------------------------------------------
__global__ void wt_transpose(const float* __restrict__ W, unsigned int* __restrict__ Wt) {
    int k = blockIdx.x;          // 0..63
    int j = threadIdx.x;         // 0..383, handles h = 2j, 2j+1
    float a = W[(size_t)(2 * j) * K_ + k];
    float b = W[(size_t)(2 * j + 1) * K_ + k];
    unsigned int u = (unsigned int)f2bf_bits(a) | ((unsigned int)f2bf_bits(b) << 16);
    Wt[k * (H_ / 2) + j] = u;
}

// ---------------------------------------------------------------------------
// Kernel 1: emit[131072][64] = features @ W + b.  bf16 MFMA 16x16x32.
// B-frags read directly from pre-transposed global Wt (L1/L2-resident),
// A-frags direct from global. No LDS, no barriers. 4 blocks/CU.
// ---------------------------------------------------------------------------
__global__ __launch_bounds__(256, 4)
void emit_gemm(const float* __restrict__ A, const unsigned short* __restrict__ Wt,
               const float* __restrict__ bias, float* __restrict__ emit) {
    const int tid  = threadIdx.x;
    const int lane = tid & 63;
    const int wid  = tid >> 6;
    const int lm   = lane & 15;   // m (A) / n (B) / col (C)
    const int lq   = lane >> 4;   // k-group

    float4v acc[2][4];
    #pragma unroll
    for (int c = 0; c < 2; ++c)
        #pragma unroll
        for (int nt = 0; nt < 4; ++nt)
            acc[c][nt] = (float4v)0.f;

    const int rowbase = blockIdx.x * 128 + wid * 16 + lm;

    for (int ks = 0; ks < 24; ++ks) {
        short8v bfrag[4];
        #pragma unroll
        for (int nt = 0; nt < 4; ++nt) {
            const uint4* bp = reinterpret_cast<const uint4*>(
                Wt + (size_t)(lm + nt * 16) * H_ + ks * 32 + lq * 8);
            BFragU bb; bb.u4 = *bp;
            bfrag[nt] = bb.s8;
        }
        #pragma unroll
        for (int c = 0; c < 2; ++c) {
            const float* ap = A + (size_t)(rowbase + c * 64) * H_ + ks * 32 + lq * 8;
            float4 a0 = *reinterpret_cast<const float4*>(ap);
            float4 a1 = *reinterpret_cast<const float4*>(ap + 4);
            __hip_bfloat162 tt[4];
            tt[0] = __float22bfloat162_rn(make_float2(a0.x, a0.y));
            tt[1] = __float22bfloat162_rn(make_float2(a0.z, a0.w));
            tt[2] = __float22bfloat162_rn(make_float2(a1.x, a1.y));
            tt[3] = __float22bfloat162_rn(make_float2(a1.z, a1.w));
            short8v afrag;
            memcpy(&afrag, tt, 16);
            #pragma unroll
            for (int nt = 0; nt < 4; ++nt)
                acc[c][nt] = __builtin_amdgcn_mfma_f32_16x16x32_bf16(
                    afrag, bfrag[nt], acc[c][nt], 0, 0, 0);
        }
    }

    // epilogue: C/D map col=lane&15, row=(lane>>4)*4+r
    float bv[4];
    #pragma unroll
    for (int nt = 0; nt < 4; ++nt) bv[nt] = bias[nt * 16 + lm];
    #pragma unroll
    for (int c = 0; c < 2; ++c) {
        int rowb = blockIdx.x * 128 + c * 64 + wid * 16 + lq * 4;
        #pragma unroll
        for (int nt = 0; nt < 4; ++nt) {
            int col = nt * 16 + lm;
            #pragma unroll
            for (int r = 0; r < 4; ++r)
                emit[(size_t)(rowb + r) * K_ + col] = acc[c][nt][r] + bv[nt];
        }
    }
}

// ---------------------------------------------------------------------------
// Kernel 2: CRF forward scan in shifted-exp space. One wave per chain.
//   q_t = s_t * exp(e_t - delta_t),  s_t[k] = sum_i q_{t-1}[i] * exp(T[i][k])
//   M accumulates delta exactly; logZ = M + log(sum_k q).
// e staged via 16-step double-buffered LDS chunks; matvec = 32 v_pk_fma_f32.
// ---------------------------------------------------------------------------
__global__ __launch_bounds__(64, 1)
void crf_scan(const float* __restrict__ emit, const float* __restrict__ T,
              const int* __restrict__ tags, const int* __restrict__ mask,
              float* __restrict__ out) {
    const int b    = blockIdx.x;
    const int lane = threadIdx.x;
    __shared__ __align__(16) float ebuf[2][16 * 64];
    __shared__ __align__(16) float qbuf[2][64];

    // sequence length (mask is prefix-true); lengths in [128, 512]
    int len = 0;
    #pragma unroll
    for (int j = 0; j < 8; ++j) len += (mask[b * L_ + j * 64 + lane] != 0);
    #pragma unroll
    for (int off = 32; off; off >>= 1) len += __shfl_xor(len, off, 64);

    // expT column pairs: et2[j] = {exp(T[2j][lane]), exp(T[2j+1][lane])}
    float2v et2[32];
    #pragma unroll
    for (int j = 0; j < 32; ++j) {
        et2[j].x = __expf(T[(2 * j) * K_ + lane]);
        et2[j].y = __expf(T[(2 * j + 1) * K_ + lane]);
    }

    const float* eb = emit + (size_t)b * L_ * K_;

    // gold-path score, lane-parallel over t
    float sc = 0.f;
    for (int t = lane; t < len; t += 64) {
        int tg = tags[b * L_ + t];
        sc += eb[(size_t)t * K_ + tg];
        if (t > 0) sc += T[tags[b * L_ + t - 1] * K_ + tg];
    }
    #pragma unroll
    for (int off = 32; off; off >>= 1) sc += __shfl_xor(sc, off, 64);

    // t = 0
    float e00 = eb[lane];
    float M = __int_as_float(__builtin_amdgcn_readfirstlane(__float_as_int(e00)));
    float q = __expf(e00 - M);
    qbuf[0][lane] = q;
    int prev_eps = 0;

    // stage chunk 0 (t = 0..15): lane covers 16 contiguous floats
    const int soff = ((lane >> 2) << 6) + ((lane & 3) << 4);
    {
        const float4* src = reinterpret_cast<const float4*>(eb + soff);
        float4 r0 = src[0], r1 = src[1], r2 = src[2], r3 = src[3];
        float4* dst = reinterpret_cast<float4*>(&ebuf[0][soff]);
        dst[0] = r0; dst[1] = r1; dst[2] = r2; dst[3] = r3;
    }

    int cur = 0;
    int t = 1;
    for (int c = 0;; ++c) {
        const int nt0  = (c + 1) << 4;
        const bool more = nt0 < len;
        float4 r0, r1, r2, r3;
        if (more) {   // prefetch next chunk into registers (16 steps to land)
            const float4* src = reinterpret_cast<const float4*>(eb + nt0 * K_ + soff);
            r0 = src[0]; r1 = src[1]; r2 = src[2]; r3 = src[3];
        }
        const int tend = more ? nt0 : len;
        for (; t < tend; ++t) {
            float e  = ebuf[cur][((t & 15) << 6) + lane];
            float ef = __int_as_float(__builtin_amdgcn_readfirstlane(__float_as_int(e)));
            float delta = (float)prev_eps * 0.69314718f + ef;
            M += delta;
            float f = __expf(e - delta);          // off the critical path

            const float4* qb4 = reinterpret_cast<const float4*>(&qbuf[(t + 1) & 1][0]);
            float2v a0 = mk2(0.f, 0.f), a1 = mk2(0.f, 0.f);
            float2v a2 = mk2(0.f, 0.f), a3 = mk2(0.f, 0.f);
            #pragma unroll
            for (int r = 0; r < 16; r += 2) {
                float4 p0 = qb4[r];
                float4 p1 = qb4[r + 1];
                a0 += mk2(p0.x, p0.y) * et2[2 * r];
                a1 += mk2(p0.z, p0.w) * et2[2 * r + 1];
                a2 += mk2(p1.x, p1.y) * et2[2 * r + 2];
                a3 += mk2(p1.z, p1.w) * et2[2 * r + 3];
            }
            float2v s2 = (a0 + a1) + (a2 + a3);
            float s = s2.x + s2.y;
            unsigned su = (unsigned)__builtin_amdgcn_readfirstlane(__float_as_int(s));
            prev_eps = (int)((su >> 23) & 0xff) - 127;   // scale estimate for next delta
            q = s * f;
            qbuf[t & 1][lane] = q;
        }
        if (!more) break;
        float4* dst = reinterpret_cast<float4*>(&ebuf[cur ^ 1][soff]);
        dst[0] = r0; dst[1] = r1; dst[2] = r2; dst[3] = r3;
        cur ^= 1;
    }

    // logZ = M + log(sum_k q)
    float z = q;
    #pragma unroll
    for (int off = 32; off; off >>= 1) z += __shfl_xor(z, off, 64);
    if (lane == 0) out[b] = M + __logf(z) - sc;
}

extern "C" void kernel_launch(void* const* d_in, const int* in_sizes, int n_in,
                              void* d_out, int out_size, void* d_ws, size_t ws_size,
                              hipStream_t stream) {
    const float* feat = (const float*)d_in[0];
    const float* W    = (const float*)d_in[1];
    const float* bias = (const float*)d_in[2];
    const float* T    = (const float*)d_in[3];
    const int*   tags = (const int*)d_in[4];
    const int*   mask = (const int*)d_in[5];
    float* out  = (float*)d_out;
    float* emit = (float*)d_ws;                                   // 33.5 MB
    unsigned int*   WtW = (unsigned int*)((char*)d_ws + WT_OFF);  // 96 KB bf16
    unsigned short* Wt  = (unsigned short*)WtW;

    hipLaunchKernelGGL(wt_transpose, dim3(K_),   dim3(H_ / 2), 0, stream, W, WtW);
    hipLaunchKernelGGL(emit_gemm,    dim3(1024), dim3(256),    0, stream, feat, Wt, bias, emit);
    hipLaunchKernelGGL(crf_scan,     dim3(B_),   dim3(64),     0, stream, emit, T, tags, mask, out);
}

// Round 3
// 729.531 us; speedup vs baseline: 1.0220x; 1.0220x over previous
//
#include <hip/hip_runtime.h>
#include <hip/hip_bf16.h>
#include <string.h>

#define B_ 256
#define L_ 512
#define H_ 768
#define K_ 64
#define WT_OFF 33554432   // emit = 131072*64*4 bytes, Wt after it

typedef float  float4v  __attribute__((ext_vector_type(4)));
typedef float  float2v  __attribute__((ext_vector_type(2)));
typedef short  short8v  __attribute__((ext_vector_type(8)));

union BFragU { uint4 u4; short8v s8; };

__device__ inline unsigned short f2bf_bits(float f) {
    union { float f; unsigned int u; } c; c.f = f;
    unsigned int u = c.u;
    u += 0x7fffu + ((u >> 16) & 1u);   // round-to-nearest-even
    return (unsigned short)(u >> 16);
}

__device__ inline float2v mk2(float x, float y) { float2v v; v.x = x; v.y = y; return v; }

// ---------------------------------------------------------------------------
// Kernel 0: Wt[k][h] = bf16(W[h][k])  (64 x 768 bf16 = 96 KB in d_ws)
// ---------------------------------------------------------------------------
__global__ void wt_transpose(const float* __restrict__ W, unsigned int* __restrict__ Wt) {
    int k = blockIdx.x;          // 0..63
    int j = threadIdx.x;         // 0..383, handles h = 2j, 2j+1
    float a = W[(size_t)(2 * j) * K_ + k];
    float b = W[(size_t)(2 * j + 1) * K_ + k];
    unsigned int u = (unsigned int)f2bf_bits(a) | ((unsigned int)f2bf_bits(b) << 16);
    Wt[k * (H_ / 2) + j] = u;
}

// ---------------------------------------------------------------------------
// Kernel 1: emit = features @ W + b, bf16 MFMA, explicit 2-stage register
// pipeline (loads for ks+1 in flight during MFMA of ks), length-skip on
// 64-row chunks via mask (prefix-true): skipped rows are never read later.
// ---------------------------------------------------------------------------
template<int NC>
struct Stage {
    uint4  b[4];
    float4 a[NC][2];
};

template<int NC>
__device__ __forceinline__ void load_stage(Stage<NC>& s, const float* __restrict__ A,
        const unsigned short* __restrict__ Wt, int rowbase, int ks, int lm, int lq) {
    #pragma unroll
    for (int nt = 0; nt < 4; ++nt)
        s.b[nt] = *reinterpret_cast<const uint4*>(
            Wt + (size_t)(lm + nt * 16) * H_ + ks * 32 + lq * 8);
    #pragma unroll
    for (int c = 0; c < NC; ++c) {
        const float* ap = A + (size_t)(rowbase + c * 64) * H_ + ks * 32 + lq * 8;
        s.a[c][0] = *reinterpret_cast<const float4*>(ap);
        s.a[c][1] = *reinterpret_cast<const float4*>(ap + 4);
    }
}

template<int NC>
__device__ __forceinline__ void consume_stage(const Stage<NC>& s, float4v acc[][4]) {
    short8v bfrag[4];
    #pragma unroll
    for (int nt = 0; nt < 4; ++nt) { BFragU u; u.u4 = s.b[nt]; bfrag[nt] = u.s8; }
    #pragma unroll
    for (int c = 0; c < NC; ++c) {
        __hip_bfloat162 tt[4];
        tt[0] = __float22bfloat162_rn(make_float2(s.a[c][0].x, s.a[c][0].y));
        tt[1] = __float22bfloat162_rn(make_float2(s.a[c][0].z, s.a[c][0].w));
        tt[2] = __float22bfloat162_rn(make_float2(s.a[c][1].x, s.a[c][1].y));
        tt[3] = __float22bfloat162_rn(make_float2(s.a[c][1].z, s.a[c][1].w));
        short8v afrag;
        memcpy(&afrag, tt, 16);
        #pragma unroll
        for (int nt = 0; nt < 4; ++nt)
            acc[c][nt] = __builtin_amdgcn_mfma_f32_16x16x32_bf16(
                afrag, bfrag[nt], acc[c][nt], 0, 0, 0);
    }
}

template<int NC>
__device__ __forceinline__ void gemm_body(const float* __restrict__ A,
        const unsigned short* __restrict__ Wt, const float* __restrict__ bias,
        float* __restrict__ emit, int blk, int tid) {
    const int lane = tid & 63;
    const int wid  = tid >> 6;
    const int lm   = lane & 15;
    const int lq   = lane >> 4;
    const int rowbase = blk * 128 + wid * 16 + lm;

    float4v acc[NC][4];
    #pragma unroll
    for (int c = 0; c < NC; ++c)
        #pragma unroll
        for (int nt = 0; nt < 4; ++nt)
            acc[c][nt] = (float4v)0.f;

    Stage<NC> s0, s1;
    load_stage<NC>(s0, A, Wt, rowbase, 0, lm, lq);
    #pragma unroll 1
    for (int ks = 0; ks < 24; ks += 2) {
        load_stage<NC>(s1, A, Wt, rowbase, ks + 1, lm, lq);
        consume_stage<NC>(s0, acc);
        load_stage<NC>(s0, A, Wt, rowbase, (ks + 2 < 24) ? ks + 2 : 23, lm, lq);
        consume_stage<NC>(s1, acc);
    }

    // epilogue: C/D map col=lane&15, row=(lane>>4)*4+r
    float bv[4];
    #pragma unroll
    for (int nt = 0; nt < 4; ++nt) bv[nt] = bias[nt * 16 + lm];
    #pragma unroll
    for (int c = 0; c < NC; ++c) {
        int rowb = blk * 128 + c * 64 + wid * 16 + lq * 4;
        #pragma unroll
        for (int nt = 0; nt < 4; ++nt) {
            int col = nt * 16 + lm;
            #pragma unroll
            for (int r = 0; r < 4; ++r)
                emit[(size_t)(rowb + r) * K_ + col] = acc[c][nt][r] + bv[nt];
        }
    }
}

__global__ __launch_bounds__(256, 2)
void emit_gemm(const float* __restrict__ A, const unsigned short* __restrict__ Wt,
               const float* __restrict__ bias, const int* __restrict__ mask,
               float* __restrict__ emit) {
    const int r0 = blockIdx.x * 128;
    // mask is flat [B][L]: mask[row] == (t < len[b]) for row = b*L + t.
    // Chunks are 64 rows, t-aligned; mask prefix-true within each b.
    if (mask[r0] == 0) return;                 // neither chunk needed
    if (mask[r0 + 64])
        gemm_body<2>(A, Wt, bias, emit, blockIdx.x, threadIdx.x);
    else
        gemm_body<1>(A, Wt, bias, emit, blockIdx.x, threadIdx.x);
}

// ---------------------------------------------------------------------------
// Kernel 2: CRF forward scan in shifted-exp space (unchanged from round 2).
// ---------------------------------------------------------------------------
__global__ __launch_bounds__(64, 1)
void crf_scan(const float* __restrict__ emit, const float* __restrict__ T,
              const int* __restrict__ tags, const int* __restrict__ mask,
              float* __restrict__ out) {
    const int b    = blockIdx.x;
    const int lane = threadIdx.x;
    __shared__ __align__(16) float ebuf[2][16 * 64];
    __shared__ __align__(16) float qbuf[2][64];

    int len = 0;
    #pragma unroll
    for (int j = 0; j < 8; ++j) len += (mask[b * L_ + j * 64 + lane] != 0);
    #pragma unroll
    for (int off = 32; off; off >>= 1) len += __shfl_xor(len, off, 64);

    float2v et2[32];
    #pragma unroll
    for (int j = 0; j < 32; ++j) {
        et2[j].x = __expf(T[(2 * j) * K_ + lane]);
        et2[j].y = __expf(T[(2 * j + 1) * K_ + lane]);
    }

    const float* eb = emit + (size_t)b * L_ * K_;

    float sc = 0.f;
    for (int t = lane; t < len; t += 64) {
        int tg = tags[b * L_ + t];
        sc += eb[(size_t)t * K_ + tg];
        if (t > 0) sc += T[tags[b * L_ + t - 1] * K_ + tg];
    }
    #pragma unroll
    for (int off = 32; off; off >>= 1) sc += __shfl_xor(sc, off, 64);

    float e00 = eb[lane];
    float M = __int_as_float(__builtin_amdgcn_readfirstlane(__float_as_int(e00)));
    float q = __expf(e00 - M);
    qbuf[0][lane] = q;
    int prev_eps = 0;

    const int soff = ((lane >> 2) << 6) + ((lane & 3) << 4);
    {
        const float4* src = reinterpret_cast<const float4*>(eb + soff);
        float4 r0 = src[0], r1 = src[1], r2 = src[2], r3 = src[3];
        float4* dst = reinterpret_cast<float4*>(&ebuf[0][soff]);
        dst[0] = r0; dst[1] = r1; dst[2] = r2; dst[3] = r3;
    }

    int cur = 0;
    int t = 1;
    for (int c = 0;; ++c) {
        const int nt0  = (c + 1) << 4;
        const bool more = nt0 < len;
        float4 r0, r1, r2, r3;
        if (more) {
            const float4* src = reinterpret_cast<const float4*>(eb + nt0 * K_ + soff);
            r0 = src[0]; r1 = src[1]; r2 = src[2]; r3 = src[3];
        }
        const int tend = more ? nt0 : len;
        for (; t < tend; ++t) {
            float e  = ebuf[cur][((t & 15) << 6) + lane];
            float ef = __int_as_float(__builtin_amdgcn_readfirstlane(__float_as_int(e)));
            float delta = (float)prev_eps * 0.69314718f + ef;
            M += delta;
            float f = __expf(e - delta);

            const float4* qb4 = reinterpret_cast<const float4*>(&qbuf[(t + 1) & 1][0]);
            float2v a0 = mk2(0.f, 0.f), a1 = mk2(0.f, 0.f);
            float2v a2 = mk2(0.f, 0.f), a3 = mk2(0.f, 0.f);
            #pragma unroll
            for (int r = 0; r < 16; r += 2) {
                float4 p0 = qb4[r];
                float4 p1 = qb4[r + 1];
                a0 += mk2(p0.x, p0.y) * et2[2 * r];
                a1 += mk2(p0.z, p0.w) * et2[2 * r + 1];
                a2 += mk2(p1.x, p1.y) * et2[2 * r + 2];
                a3 += mk2(p1.z, p1.w) * et2[2 * r + 3];
            }
            float2v s2 = (a0 + a1) + (a2 + a3);
            float s = s2.x + s2.y;
            unsigned su = (unsigned)__builtin_amdgcn_readfirstlane(__float_as_int(s));
            prev_eps = (int)((su >> 23) & 0xff) - 127;
            q = s * f;
            qbuf[t & 1][lane] = q;
        }
        if (!more) break;
        float4* dst = reinterpret_cast<float4*>(&ebuf[cur ^ 1][soff]);
        dst[0] = r0; dst[1] = r1; dst[2] = r2; dst[3] = r3;
        cur ^= 1;
    }

    float z = q;
    #pragma unroll
    for (int off = 32; off; off >>= 1) z += __shfl_xor(z, off, 64);
    if (lane == 0) out[b] = M + __logf(z) - sc;
}

extern "C" void kernel_launch(void* const* d_in, const int* in_sizes, int n_in,
                              void* d_out, int out_size, void* d_ws, size_t ws_size,
                              hipStream_t stream) {
    const float* feat = (const float*)d_in[0];
    const float* W    = (const float*)d_in[1];
    const float* bias = (const float*)d_in[2];
    const float* T    = (const float*)d_in[3];
    const int*   tags = (const int*)d_in[4];
    const int*   mask = (const int*)d_in[5];
    float* out  = (float*)d_out;
    float* emit = (float*)d_ws;                                   // 33.5 MB
    unsigned int*   WtW = (unsigned int*)((char*)d_ws + WT_OFF);  // 96 KB bf16
    unsigned short* Wt  = (unsigned short*)WtW;

    hipLaunchKernelGGL(wt_transpose, dim3(K_),   dim3(H_ / 2), 0, stream, W, WtW);
    hipLaunchKernelGGL(emit_gemm,    dim3(1024), dim3(256),    0, stream, feat, Wt, bias, mask, emit);
    hipLaunchKernelGGL(crf_scan,     dim3(B_),   dim3(64),     0, stream, emit, T, tags, mask, out);
}